// Round 1
// baseline (248.810 us; speedup 1.0000x reference)
//
#include <hip/hip_runtime.h>
#include <hip/hip_bf16.h>

using bf8_t = __attribute__((ext_vector_type(8))) short;
using f32x4 = __attribute__((ext_vector_type(4))) float;

constexpr int B_   = 8;
constexpr int N_   = 300;
constexpr int L_   = 4096;
constexpr int C_   = 256;
constexpr int H_   = 8;
constexpr int NPAD = 320;          // 5 row-tiles of 64
constexpr float SCALE = 0.125f;    // (2*32)^-0.5

__device__ __forceinline__ unsigned short f2b(float f) {
  unsigned u = __float_as_uint(f);
  u += 0x7FFFu + ((u >> 16) & 1u);          // RNE
  return (unsigned short)(u >> 16);
}

// convert 16 contiguous f32 -> 16 bf16 into LDS (dst 16B-aligned)
__device__ __forceinline__ void stage_cvt16(unsigned short* dst, const float* src) {
#pragma unroll
  for (int half = 0; half < 2; ++half) {
    f32x4 x0 = *(const f32x4*)(src + half * 8);
    f32x4 x1 = *(const f32x4*)(src + half * 8 + 4);
    bf8_t v;
#pragma unroll
    for (int j = 0; j < 4; ++j) { v[j] = (short)f2b(x0[j]); v[4 + j] = (short)f2b(x1[j]); }
    *(bf8_t*)(dst + half * 8) = v;
  }
}

__device__ __forceinline__ void stage_zero16(unsigned short* dst) {
  bf8_t v;
#pragma unroll
  for (int j = 0; j < 8; ++j) v[j] = 0;
  *(bf8_t*)(dst) = v;
  *(bf8_t*)(dst + 8) = v;
}

// ---------------- Q-side projections: qc,qp,qs -> Qcat[b][h][n][64] (scaled) ----
__global__ __launch_bounds__(256) void qproj_k(
    const float* __restrict__ xq, const float* __restrict__ xp, const float* __restrict__ xs,
    const float* __restrict__ Wqc, const float* __restrict__ bqc,
    const float* __restrict__ Wqp, const float* __restrict__ bqp,
    const float* __restrict__ Wqs, const float* __restrict__ bqs,
    unsigned short* __restrict__ Qcat)
{
  __shared__ __align__(16) unsigned short Al[3][64][72];
  __shared__ __align__(16) unsigned short Bl[3][64][72];
  const int b = blockIdx.z, n0 = blockIdx.y * 64, d0 = blockIdx.x * 64;
  const int tid = threadIdx.x, lane = tid & 63, wv = tid >> 6;
  const int wm = wv >> 1, wn = wv & 1;
  const int sr = tid >> 2, sc = (tid & 3) * 16;
  const int fr = lane & 15, fg = lane >> 4;
  const float* Ax[3] = {xq, xp, xs};
  const float* Bx[3] = {Wqc, Wqp, Wqs};
  const bool arow_ok = (n0 + sr) < N_;
  f32x4 acc[3][2][2] = {};

  for (int kt = 0; kt < 4; ++kt) {
    const int k0 = kt * 64;
#pragma unroll
    for (int i = 0; i < 3; ++i) {
      if (arow_ok) stage_cvt16(&Al[i][sr][sc], Ax[i] + ((size_t)b * N_ + n0 + sr) * C_ + k0 + sc);
      else         stage_zero16(&Al[i][sr][sc]);
      stage_cvt16(&Bl[i][sr][sc], Bx[i] + (size_t)(d0 + sr) * C_ + k0 + sc);
    }
    __syncthreads();
#pragma unroll
    for (int kh = 0; kh < 2; ++kh) {
      const int ko = kh * 32 + 8 * fg;
      bf8_t af[3][2], bq[3][2];
#pragma unroll
      for (int i = 0; i < 3; ++i)
#pragma unroll
        for (int m = 0; m < 2; ++m) {
          af[i][m] = *(const bf8_t*)&Al[i][wm * 32 + m * 16 + fr][ko];
          bq[i][m] = *(const bf8_t*)&Bl[i][wn * 32 + m * 16 + fr][ko];
        }
#pragma unroll
      for (int i = 0; i < 3; ++i)
#pragma unroll
        for (int m = 0; m < 2; ++m)
#pragma unroll
          for (int n = 0; n < 2; ++n)
            acc[i][m][n] = __builtin_amdgcn_mfma_f32_16x16x32_bf16(af[i][m], bq[i][n], acc[i][m][n], 0, 0, 0);
    }
    __syncthreads();
  }
#pragma unroll
  for (int m = 0; m < 2; ++m)
#pragma unroll
    for (int nn = 0; nn < 2; ++nn) {
      const int d = d0 + wn * 32 + nn * 16 + fr;
      const int h = d >> 5, dh = d & 31;
      const float b1 = bqc[d] + bqp[d];
      const float b2 = bqs[d];
#pragma unroll
      for (int r = 0; r < 4; ++r) {
        const int n = n0 + wm * 32 + m * 16 + fg * 4 + r;
        const size_t qi = (((size_t)b * H_ + h) * NPAD + n) * 64 + dh;
        float v1 = 0.f, v2 = 0.f;
        if (n < N_) {
          v1 = (acc[0][m][nn][r] + acc[1][m][nn][r] + b1) * SCALE;
          v2 = (acc[2][m][nn][r] + b2) * SCALE;
        }
        Qcat[qi]      = f2b(v1);
        Qcat[qi + 32] = f2b(v2);
      }
    }
}

// ---------------- K-side projections: kc,kp,v -> Kcat[b][h][l][64], V[b][h][l][32]
__global__ __launch_bounds__(256) void kvproj_k(
    const float* __restrict__ xk, const float* __restrict__ xp, const float* __restrict__ xv,
    const float* __restrict__ Wkc, const float* __restrict__ bkc,
    const float* __restrict__ Wkp, const float* __restrict__ bkp,
    const float* __restrict__ Wv,  const float* __restrict__ bv,
    unsigned short* __restrict__ Kcat, unsigned short* __restrict__ Vh)
{
  __shared__ __align__(16) unsigned short Al[3][64][72];
  __shared__ __align__(16) unsigned short Bl[3][64][72];
  const int b = blockIdx.z, l0 = blockIdx.y * 64, d0 = blockIdx.x * 64;
  const int tid = threadIdx.x, lane = tid & 63, wv = tid >> 6;
  const int wm = wv >> 1, wn = wv & 1;
  const int sr = tid >> 2, sc = (tid & 3) * 16;
  const int fr = lane & 15, fg = lane >> 4;
  const float* Ax[3] = {xk, xp, xv};
  const float* Bx[3] = {Wkc, Wkp, Wv};
  f32x4 acc[3][2][2] = {};

  for (int kt = 0; kt < 4; ++kt) {
    const int k0 = kt * 64;
#pragma unroll
    for (int i = 0; i < 3; ++i) {
      stage_cvt16(&Al[i][sr][sc], Ax[i] + ((size_t)b * L_ + l0 + sr) * C_ + k0 + sc);
      stage_cvt16(&Bl[i][sr][sc], Bx[i] + (size_t)(d0 + sr) * C_ + k0 + sc);
    }
    __syncthreads();
#pragma unroll
    for (int kh = 0; kh < 2; ++kh) {
      const int ko = kh * 32 + 8 * fg;
      bf8_t af[3][2], bq[3][2];
#pragma unroll
      for (int i = 0; i < 3; ++i)
#pragma unroll
        for (int m = 0; m < 2; ++m) {
          af[i][m] = *(const bf8_t*)&Al[i][wm * 32 + m * 16 + fr][ko];
          bq[i][m] = *(const bf8_t*)&Bl[i][wn * 32 + m * 16 + fr][ko];
        }
#pragma unroll
      for (int i = 0; i < 3; ++i)
#pragma unroll
        for (int m = 0; m < 2; ++m)
#pragma unroll
          for (int n = 0; n < 2; ++n)
            acc[i][m][n] = __builtin_amdgcn_mfma_f32_16x16x32_bf16(af[i][m], bq[i][n], acc[i][m][n], 0, 0, 0);
    }
    __syncthreads();
  }
#pragma unroll
  for (int m = 0; m < 2; ++m)
#pragma unroll
    for (int nn = 0; nn < 2; ++nn) {
      const int d = d0 + wn * 32 + nn * 16 + fr;
      const int h = d >> 5, dh = d & 31;
      const float b1 = bkc[d], b2 = bkp[d], b3 = bv[d];
#pragma unroll
      for (int r = 0; r < 4; ++r) {
        const int l = l0 + wm * 32 + m * 16 + fg * 4 + r;
        const size_t base = ((size_t)b * H_ + h) * L_ + l;
        const float kc = acc[0][m][nn][r] + b1;
        const float kp = acc[1][m][nn][r] + b2;
        const float vv = acc[2][m][nn][r] + b3;
        Kcat[base * 64 + dh]      = f2b(kc + kp);
        Kcat[base * 64 + 32 + dh] = f2b(kp);
        Vh[base * 32 + dh]        = f2b(vv);
      }
    }
}

// ---------------- flash attention: Qcat x Kcat -> softmax -> V ------------------
__global__ __launch_bounds__(256) void attn_k(
    const unsigned short* __restrict__ Qcat, const unsigned short* __restrict__ Kcat,
    const unsigned short* __restrict__ Vh, unsigned short* __restrict__ aout)
{
  __shared__ __align__(16) unsigned short Kl[64][72];
  __shared__ __align__(16) unsigned short Vt[32][72];
  __shared__ __align__(16) unsigned short Pl[64][72];
  const int qt = blockIdx.x, h = blockIdx.y, b = blockIdx.z;
  const int n0 = qt * 64;
  const int tid = threadIdx.x, lane = tid & 63, wv = tid >> 6;
  const int fr = lane & 15, fg = lane >> 4;

  // hoist Q fragments (rows n0+wv*16+fr, always < NPAD; pad rows are zeros)
  const unsigned short* Qb = Qcat + ((size_t)b * H_ + h) * NPAD * 64;
  bf8_t qf[2];
  {
    const int qrow = n0 + wv * 16 + fr;
#pragma unroll
    for (int kh = 0; kh < 2; ++kh)
      qf[kh] = *(const bf8_t*)&Qb[(size_t)qrow * 64 + kh * 32 + 8 * fg];
  }
  float m_r[4], l_r[4];
#pragma unroll
  for (int r = 0; r < 4; ++r) { m_r[r] = -1e30f; l_r[r] = 0.f; }
  f32x4 o[2] = {};

  const unsigned short* KB = Kcat + ((size_t)b * H_ + h) * L_ * 64;
  const unsigned short* VB = Vh   + ((size_t)b * H_ + h) * L_ * 32;
  const int sr = tid >> 2;

  for (int kv0 = 0; kv0 < L_; kv0 += 64) {
    {  // stage K tile (64x64)
      const int c0 = (tid & 3) * 16;
      const unsigned short* src = KB + (size_t)(kv0 + sr) * 64 + c0;
      *(bf8_t*)&Kl[sr][c0]     = *(const bf8_t*)src;
      *(bf8_t*)&Kl[sr][c0 + 8] = *(const bf8_t*)(src + 8);
    }
    {  // stage V tile transposed (Vt[dh][n])
      const int vn = tid >> 2, dh0 = (tid & 3) * 8;
      bf8_t v = *(const bf8_t*)&VB[(size_t)(kv0 + vn) * 32 + dh0];
#pragma unroll
      for (int j = 0; j < 8; ++j) Vt[dh0 + j][vn] = (unsigned short)v[j];
    }
    __syncthreads();

    // scores: S[16 rows][64 cols] per wave
    f32x4 s[4] = {};
#pragma unroll
    for (int kh = 0; kh < 2; ++kh) {
      const int ko = kh * 32 + 8 * fg;
#pragma unroll
      for (int nf = 0; nf < 4; ++nf) {
        bf8_t kf = *(const bf8_t*)&Kl[nf * 16 + fr][ko];
        s[nf] = __builtin_amdgcn_mfma_f32_16x16x32_bf16(qf[kh], kf, s[nf], 0, 0, 0);
      }
    }
    // online softmax (row = fg*4 + r, cols across the 16 lanes of the group)
#pragma unroll
    for (int r = 0; r < 4; ++r) {
      float mx = fmaxf(fmaxf(s[0][r], s[1][r]), fmaxf(s[2][r], s[3][r]));
      mx = fmaxf(mx, __shfl_xor(mx, 1));
      mx = fmaxf(mx, __shfl_xor(mx, 2));
      mx = fmaxf(mx, __shfl_xor(mx, 4));
      mx = fmaxf(mx, __shfl_xor(mx, 8));
      const float mnew = fmaxf(m_r[r], mx);
      const float corr = __expf(m_r[r] - mnew);
      float ps = 0.f;
#pragma unroll
      for (int nf = 0; nf < 4; ++nf) {
        const float p = __expf(s[nf][r] - mnew);
        s[nf][r] = p;
        ps += p;
      }
      ps += __shfl_xor(ps, 1);
      ps += __shfl_xor(ps, 2);
      ps += __shfl_xor(ps, 4);
      ps += __shfl_xor(ps, 8);
      l_r[r] = l_r[r] * corr + ps;
      m_r[r] = mnew;
      o[0][r] *= corr;
      o[1][r] *= corr;
    }
    // P -> LDS (same-wave region; no barrier needed before re-read)
    {
      const int prow0 = wv * 16 + fg * 4;
#pragma unroll
      for (int nf = 0; nf < 4; ++nf)
#pragma unroll
        for (int r = 0; r < 4; ++r)
          Pl[prow0 + r][nf * 16 + fr] = f2b(s[nf][r]);
    }
    // PV
#pragma unroll
    for (int kh = 0; kh < 2; ++kh) {
      const int ko = kh * 32 + 8 * fg;
      bf8_t pf = *(const bf8_t*)&Pl[wv * 16 + fr][ko];
#pragma unroll
      for (int df = 0; df < 2; ++df) {
        bf8_t vf = *(const bf8_t*)&Vt[df * 16 + fr][ko];
        o[df] = __builtin_amdgcn_mfma_f32_16x16x32_bf16(pf, vf, o[df], 0, 0, 0);
      }
    }
    __syncthreads();
  }
  // normalize + write attn_out[b][n][h*32+dh]
#pragma unroll
  for (int df = 0; df < 2; ++df)
#pragma unroll
    for (int r = 0; r < 4; ++r) {
      const int n = n0 + wv * 16 + fg * 4 + r;
      if (n < N_) {
        const float val = o[df][r] / l_r[r];
        aout[((size_t)b * NPAD + n) * C_ + h * 32 + df * 16 + fr] = f2b(val);
      }
    }
}

// ---------------- output projection + bias + residual ---------------------------
__global__ __launch_bounds__(256) void oproj_k(
    const unsigned short* __restrict__ aout, const float* __restrict__ Wo,
    const float* __restrict__ bo, const float* __restrict__ query,
    float* __restrict__ out)
{
  __shared__ __align__(16) unsigned short Al[64][72];
  __shared__ __align__(16) unsigned short Bl[64][72];
  const int b = blockIdx.z, n0 = blockIdx.y * 64, d0 = blockIdx.x * 64;
  const int tid = threadIdx.x, lane = tid & 63, wv = tid >> 6;
  const int wm = wv >> 1, wn = wv & 1;
  const int sr = tid >> 2, sc = (tid & 3) * 16;
  const int fr = lane & 15, fg = lane >> 4;
  f32x4 acc[2][2] = {};

  for (int kt = 0; kt < 4; ++kt) {
    const int k0 = kt * 64;
    {  // A: bf16 copy from attn_out (rows up to NPAD are allocated)
      const unsigned short* src = aout + ((size_t)b * NPAD + n0 + sr) * C_ + k0 + sc;
      *(bf8_t*)&Al[sr][sc]     = *(const bf8_t*)src;
      *(bf8_t*)&Al[sr][sc + 8] = *(const bf8_t*)(src + 8);
    }
    stage_cvt16(&Bl[sr][sc], Wo + (size_t)(d0 + sr) * C_ + k0 + sc);
    __syncthreads();
#pragma unroll
    for (int kh = 0; kh < 2; ++kh) {
      const int ko = kh * 32 + 8 * fg;
      bf8_t af[2], bq[2];
#pragma unroll
      for (int m = 0; m < 2; ++m) {
        af[m] = *(const bf8_t*)&Al[wm * 32 + m * 16 + fr][ko];
        bq[m] = *(const bf8_t*)&Bl[wn * 32 + m * 16 + fr][ko];
      }
#pragma unroll
      for (int m = 0; m < 2; ++m)
#pragma unroll
        for (int n = 0; n < 2; ++n)
          acc[m][n] = __builtin_amdgcn_mfma_f32_16x16x32_bf16(af[m], bq[n], acc[m][n], 0, 0, 0);
    }
    __syncthreads();
  }
#pragma unroll
  for (int m = 0; m < 2; ++m)
#pragma unroll
    for (int nn = 0; nn < 2; ++nn) {
      const int d = d0 + wn * 32 + nn * 16 + fr;
      const float bb = bo[d];
#pragma unroll
      for (int r = 0; r < 4; ++r) {
        const int n = n0 + wm * 32 + m * 16 + fg * 4 + r;
        if (n < N_) {
          const size_t gi = ((size_t)b * N_ + n) * C_ + d;
          out[gi] = acc[m][nn][r] + bb + query[gi];
        }
      }
    }
}

extern "C" void kernel_launch(void* const* d_in, const int* in_sizes, int n_in,
                              void* d_out, int out_size, void* d_ws, size_t ws_size,
                              hipStream_t stream)
{
  const float* query = (const float*)d_in[0];
  const float* key   = (const float*)d_in[1];
  const float* value = (const float*)d_in[2];
  const float* qpos  = (const float*)d_in[3];
  const float* kpos  = (const float*)d_in[4];
  const float* qsine = (const float*)d_in[5];
  const float* Wqc = (const float*)d_in[6];  const float* bqc = (const float*)d_in[7];
  const float* Wqp = (const float*)d_in[8];  const float* bqp = (const float*)d_in[9];
  const float* Wqs = (const float*)d_in[10]; const float* bqs = (const float*)d_in[11];
  const float* Wkc = (const float*)d_in[12]; const float* bkc = (const float*)d_in[13];
  const float* Wkp = (const float*)d_in[14]; const float* bkp = (const float*)d_in[15];
  const float* Wv  = (const float*)d_in[16]; const float* bv  = (const float*)d_in[17];
  const float* Wo  = (const float*)d_in[18]; const float* bo  = (const float*)d_in[19];

  // workspace layout (bf16 buffers)
  const size_t qcat_b = (size_t)B_ * H_ * NPAD * 64 * 2;   //  2.62 MB
  const size_t kcat_b = (size_t)B_ * H_ * L_ * 64 * 2;     // 33.55 MB
  const size_t vh_b   = (size_t)B_ * H_ * L_ * 32 * 2;     // 16.78 MB
  const size_t aout_b = (size_t)B_ * NPAD * C_ * 2;        //  1.31 MB
  if (ws_size < qcat_b + kcat_b + vh_b + aout_b) return;   // fail loudly (validation will catch)
  char* ws = (char*)d_ws;
  unsigned short* Qcat = (unsigned short*)(ws);
  unsigned short* Kcat = (unsigned short*)(ws + qcat_b);
  unsigned short* Vh   = (unsigned short*)(ws + qcat_b + kcat_b);
  unsigned short* aout = (unsigned short*)(ws + qcat_b + kcat_b + vh_b);
  float* out = (float*)d_out;

  qproj_k <<<dim3(4, 5, 8),  256, 0, stream>>>(query, qpos, qsine, Wqc, bqc, Wqp, bqp, Wqs, bqs, Qcat);
  kvproj_k<<<dim3(4, 64, 8), 256, 0, stream>>>(key, kpos, value, Wkc, bkc, Wkp, bkp, Wv, bv, Kcat, Vh);
  attn_k  <<<dim3(5, 8, 8),  256, 0, stream>>>(Qcat, Kcat, Vh, aout);
  oproj_k <<<dim3(4, 5, 8),  256, 0, stream>>>(aout, Wo, bo, query, out);
}

// Round 2
// 188.276 us; speedup vs baseline: 1.3215x; 1.3215x over previous
//
#include <hip/hip_runtime.h>
#include <hip/hip_bf16.h>

using bf8_t = __attribute__((ext_vector_type(8))) short;
using f32x4 = __attribute__((ext_vector_type(4))) float;

constexpr int B_   = 8;
constexpr int N_   = 300;
constexpr int L_   = 4096;
constexpr int C_   = 256;
constexpr int H_   = 8;
constexpr int NPAD = 320;          // 5 row-tiles of 64
constexpr int QT_  = 5;            // q tiles of 64
constexpr int SPL_ = 4;            // KV splits (flash-decoding)
constexpr int KVS_ = L_ / SPL_;    // 1024 keys per split
constexpr float SCALE = 0.125f;    // (2*32)^-0.5

__device__ __forceinline__ unsigned short f2b(float f) {
  unsigned u = __float_as_uint(f);
  u += 0x7FFFu + ((u >> 16) & 1u);          // RNE
  return (unsigned short)(u >> 16);
}

// convert 16 contiguous f32 -> 16 bf16 into LDS (dst 16B-aligned)
__device__ __forceinline__ void stage_cvt16(unsigned short* dst, const float* src) {
#pragma unroll
  for (int half = 0; half < 2; ++half) {
    f32x4 x0 = *(const f32x4*)(src + half * 8);
    f32x4 x1 = *(const f32x4*)(src + half * 8 + 4);
    bf8_t v;
#pragma unroll
    for (int j = 0; j < 4; ++j) { v[j] = (short)f2b(x0[j]); v[4 + j] = (short)f2b(x1[j]); }
    *(bf8_t*)(dst + half * 8) = v;
  }
}

__device__ __forceinline__ void stage_zero16(unsigned short* dst) {
  bf8_t v;
#pragma unroll
  for (int j = 0; j < 8; ++j) v[j] = 0;
  *(bf8_t*)(dst) = v;
  *(bf8_t*)(dst + 8) = v;
}

// ---------------- Q-side projections: qc,qp,qs -> Qcat[b][h][n][64] (scaled) ----
// sequential-i through one LDS pair (18 KB) for occupancy
__global__ __launch_bounds__(256) void qproj_k(
    const float* __restrict__ xq, const float* __restrict__ xp, const float* __restrict__ xs,
    const float* __restrict__ Wqc, const float* __restrict__ bqc,
    const float* __restrict__ Wqp, const float* __restrict__ bqp,
    const float* __restrict__ Wqs, const float* __restrict__ bqs,
    unsigned short* __restrict__ Qcat)
{
  __shared__ __align__(16) unsigned short Al[64][72];
  __shared__ __align__(16) unsigned short Bl[64][72];
  const int b = blockIdx.z, n0 = blockIdx.y * 64, d0 = blockIdx.x * 64;
  const int tid = threadIdx.x, lane = tid & 63, wv = tid >> 6;
  const int wm = wv >> 1, wn = wv & 1;
  const int sr = tid >> 2, sc = (tid & 3) * 16;
  const int fr = lane & 15, fg = lane >> 4;
  const float* Ax[3] = {xq, xp, xs};
  const float* Bx[3] = {Wqc, Wqp, Wqs};
  const bool arow_ok = (n0 + sr) < N_;
  f32x4 acc[3][2][2] = {};

  for (int kt = 0; kt < 4; ++kt) {
    const int k0 = kt * 64;
#pragma unroll
    for (int i = 0; i < 3; ++i) {
      if (arow_ok) stage_cvt16(&Al[sr][sc], Ax[i] + ((size_t)b * N_ + n0 + sr) * C_ + k0 + sc);
      else         stage_zero16(&Al[sr][sc]);
      stage_cvt16(&Bl[sr][sc], Bx[i] + (size_t)(d0 + sr) * C_ + k0 + sc);
      __syncthreads();
#pragma unroll
      for (int kh = 0; kh < 2; ++kh) {
        const int ko = kh * 32 + 8 * fg;
        bf8_t af[2], bq[2];
#pragma unroll
        for (int m = 0; m < 2; ++m) {
          af[m] = *(const bf8_t*)&Al[wm * 32 + m * 16 + fr][ko];
          bq[m] = *(const bf8_t*)&Bl[wn * 32 + m * 16 + fr][ko];
        }
#pragma unroll
        for (int m = 0; m < 2; ++m)
#pragma unroll
          for (int n = 0; n < 2; ++n)
            acc[i][m][n] = __builtin_amdgcn_mfma_f32_16x16x32_bf16(af[m], bq[n], acc[i][m][n], 0, 0, 0);
      }
      __syncthreads();
    }
  }
#pragma unroll
  for (int m = 0; m < 2; ++m)
#pragma unroll
    for (int nn = 0; nn < 2; ++nn) {
      const int d = d0 + wn * 32 + nn * 16 + fr;
      const int h = d >> 5, dh = d & 31;
      const float b1 = bqc[d] + bqp[d];
      const float b2 = bqs[d];
#pragma unroll
      for (int r = 0; r < 4; ++r) {
        const int n = n0 + wm * 32 + m * 16 + fg * 4 + r;
        const size_t qi = (((size_t)b * H_ + h) * NPAD + n) * 64 + dh;
        float v1 = 0.f, v2 = 0.f;
        if (n < N_) {
          v1 = (acc[0][m][nn][r] + acc[1][m][nn][r] + b1) * SCALE;
          v2 = (acc[2][m][nn][r] + b2) * SCALE;
        }
        Qcat[qi]      = f2b(v1);
        Qcat[qi + 32] = f2b(v2);
      }
    }
}

// ---------------- K-side projections: kc,kp,v -> Kcat[b][h][l][64], V[b][h][l][32]
// sequential-i through one LDS pair (18 KB) for occupancy
__global__ __launch_bounds__(256) void kvproj_k(
    const float* __restrict__ xk, const float* __restrict__ xp, const float* __restrict__ xv,
    const float* __restrict__ Wkc, const float* __restrict__ bkc,
    const float* __restrict__ Wkp, const float* __restrict__ bkp,
    const float* __restrict__ Wv,  const float* __restrict__ bv,
    unsigned short* __restrict__ Kcat, unsigned short* __restrict__ Vh)
{
  __shared__ __align__(16) unsigned short Al[64][72];
  __shared__ __align__(16) unsigned short Bl[64][72];
  const int b = blockIdx.z, l0 = blockIdx.y * 64, d0 = blockIdx.x * 64;
  const int tid = threadIdx.x, lane = tid & 63, wv = tid >> 6;
  const int wm = wv >> 1, wn = wv & 1;
  const int sr = tid >> 2, sc = (tid & 3) * 16;
  const int fr = lane & 15, fg = lane >> 4;
  const float* Ax[3] = {xk, xp, xv};
  const float* Bx[3] = {Wkc, Wkp, Wv};
  f32x4 acc[3][2][2] = {};

  for (int kt = 0; kt < 4; ++kt) {
    const int k0 = kt * 64;
#pragma unroll
    for (int i = 0; i < 3; ++i) {
      stage_cvt16(&Al[sr][sc], Ax[i] + ((size_t)b * L_ + l0 + sr) * C_ + k0 + sc);
      stage_cvt16(&Bl[sr][sc], Bx[i] + (size_t)(d0 + sr) * C_ + k0 + sc);
      __syncthreads();
#pragma unroll
      for (int kh = 0; kh < 2; ++kh) {
        const int ko = kh * 32 + 8 * fg;
        bf8_t af[2], bq[2];
#pragma unroll
        for (int m = 0; m < 2; ++m) {
          af[m] = *(const bf8_t*)&Al[wm * 32 + m * 16 + fr][ko];
          bq[m] = *(const bf8_t*)&Bl[wn * 32 + m * 16 + fr][ko];
        }
#pragma unroll
        for (int m = 0; m < 2; ++m)
#pragma unroll
          for (int n = 0; n < 2; ++n)
            acc[i][m][n] = __builtin_amdgcn_mfma_f32_16x16x32_bf16(af[m], bq[n], acc[i][m][n], 0, 0, 0);
      }
      __syncthreads();
    }
  }
#pragma unroll
  for (int m = 0; m < 2; ++m)
#pragma unroll
    for (int nn = 0; nn < 2; ++nn) {
      const int d = d0 + wn * 32 + nn * 16 + fr;
      const int h = d >> 5, dh = d & 31;
      const float b1 = bkc[d], b2 = bkp[d], b3 = bv[d];
#pragma unroll
      for (int r = 0; r < 4; ++r) {
        const int l = l0 + wm * 32 + m * 16 + fg * 4 + r;
        const size_t base = ((size_t)b * H_ + h) * L_ + l;
        const float kc = acc[0][m][nn][r] + b1;
        const float kp = acc[1][m][nn][r] + b2;
        const float vv = acc[2][m][nn][r] + b3;
        Kcat[base * 64 + dh]      = f2b(kc + kp);
        Kcat[base * 64 + 32 + dh] = f2b(kp);
        Vh[base * 32 + dh]        = f2b(vv);
      }
    }
}

// ---------------- flash attention (split-K over L): partial o,m,l per split ----
__global__ __launch_bounds__(256) void attn_k(
    const unsigned short* __restrict__ Qcat, const unsigned short* __restrict__ Kcat,
    const unsigned short* __restrict__ Vh,
    float* __restrict__ PO, float* __restrict__ PM, float* __restrict__ PLs)
{
  __shared__ __align__(16) unsigned short Kl[64][72];
  __shared__ __align__(16) unsigned short Vt[32][72];
  __shared__ __align__(16) unsigned short Pl[64][72];
  const int qt = blockIdx.x >> 2, s = blockIdx.x & 3;
  const int h = blockIdx.y, b = blockIdx.z;
  const int n0 = qt * 64;
  const int tid = threadIdx.x, lane = tid & 63, wv = tid >> 6;
  const int fr = lane & 15, fg = lane >> 4;

  // hoist Q fragments (rows n0+wv*16+fr, always < NPAD; pad rows are zeros)
  const unsigned short* Qb = Qcat + ((size_t)b * H_ + h) * NPAD * 64;
  bf8_t qf[2];
  {
    const int qrow = n0 + wv * 16 + fr;
#pragma unroll
    for (int kh = 0; kh < 2; ++kh)
      qf[kh] = *(const bf8_t*)&Qb[(size_t)qrow * 64 + kh * 32 + 8 * fg];
  }
  float m_r[4], l_r[4];
#pragma unroll
  for (int r = 0; r < 4; ++r) { m_r[r] = -1e30f; l_r[r] = 0.f; }
  f32x4 o[2] = {};

  const unsigned short* KB = Kcat + ((size_t)b * H_ + h) * L_ * 64;
  const unsigned short* VB = Vh   + ((size_t)b * H_ + h) * L_ * 32;
  const int sr = tid >> 2;

  for (int kv0 = s * KVS_; kv0 < (s + 1) * KVS_; kv0 += 64) {
    {  // stage K tile (64x64)
      const int c0 = (tid & 3) * 16;
      const unsigned short* src = KB + (size_t)(kv0 + sr) * 64 + c0;
      *(bf8_t*)&Kl[sr][c0]     = *(const bf8_t*)src;
      *(bf8_t*)&Kl[sr][c0 + 8] = *(const bf8_t*)(src + 8);
    }
    {  // stage V tile transposed (Vt[dh][n])
      const int vn = tid >> 2, dh0 = (tid & 3) * 8;
      bf8_t v = *(const bf8_t*)&VB[(size_t)(kv0 + vn) * 32 + dh0];
#pragma unroll
      for (int j = 0; j < 8; ++j) Vt[dh0 + j][vn] = (unsigned short)v[j];
    }
    __syncthreads();

    // scores: S[16 rows][64 cols] per wave
    f32x4 sc[4] = {};
#pragma unroll
    for (int kh = 0; kh < 2; ++kh) {
      const int ko = kh * 32 + 8 * fg;
#pragma unroll
      for (int nf = 0; nf < 4; ++nf) {
        bf8_t kf = *(const bf8_t*)&Kl[nf * 16 + fr][ko];
        sc[nf] = __builtin_amdgcn_mfma_f32_16x16x32_bf16(qf[kh], kf, sc[nf], 0, 0, 0);
      }
    }
    // online softmax (row = fg*4 + r, cols across the 16 lanes of the group)
#pragma unroll
    for (int r = 0; r < 4; ++r) {
      float mx = fmaxf(fmaxf(sc[0][r], sc[1][r]), fmaxf(sc[2][r], sc[3][r]));
      mx = fmaxf(mx, __shfl_xor(mx, 1));
      mx = fmaxf(mx, __shfl_xor(mx, 2));
      mx = fmaxf(mx, __shfl_xor(mx, 4));
      mx = fmaxf(mx, __shfl_xor(mx, 8));
      const float mnew = fmaxf(m_r[r], mx);
      const float corr = __expf(m_r[r] - mnew);
      float ps = 0.f;
#pragma unroll
      for (int nf = 0; nf < 4; ++nf) {
        const float p = __expf(sc[nf][r] - mnew);
        sc[nf][r] = p;
        ps += p;
      }
      ps += __shfl_xor(ps, 1);
      ps += __shfl_xor(ps, 2);
      ps += __shfl_xor(ps, 4);
      ps += __shfl_xor(ps, 8);
      l_r[r] = l_r[r] * corr + ps;
      m_r[r] = mnew;
      o[0][r] *= corr;
      o[1][r] *= corr;
    }
    // P -> LDS (same-wave region; no barrier needed before re-read)
    {
      const int prow0 = wv * 16 + fg * 4;
#pragma unroll
      for (int nf = 0; nf < 4; ++nf)
#pragma unroll
        for (int r = 0; r < 4; ++r)
          Pl[prow0 + r][nf * 16 + fr] = f2b(sc[nf][r]);
    }
    // PV
#pragma unroll
    for (int kh = 0; kh < 2; ++kh) {
      const int ko = kh * 32 + 8 * fg;
      bf8_t pf = *(const bf8_t*)&Pl[wv * 16 + fr][ko];
#pragma unroll
      for (int df = 0; df < 2; ++df) {
        bf8_t vf = *(const bf8_t*)&Vt[df * 16 + fr][ko];
        o[df] = __builtin_amdgcn_mfma_f32_16x16x32_bf16(pf, vf, o[df], 0, 0, 0);
      }
    }
    __syncthreads();
  }
  // write unnormalized partials
  const int rec = (((b * H_) + h) * QT_ + qt) * SPL_ + s;
  const int row0 = wv * 16 + fg * 4;
#pragma unroll
  for (int r = 0; r < 4; ++r) {
    if (fr == 0) {
      PM [rec * 64 + row0 + r] = m_r[r];
      PLs[rec * 64 + row0 + r] = l_r[r];
    }
#pragma unroll
    for (int df = 0; df < 2; ++df)
      PO[((size_t)rec * 64 + row0 + r) * 32 + df * 16 + fr] = o[df][r];
  }
}

// ---------------- combine splits -> aout (bf16) --------------------------------
__global__ __launch_bounds__(256) void combine_k(
    const float* __restrict__ PO, const float* __restrict__ PM, const float* __restrict__ PLs,
    unsigned short* __restrict__ aout)
{
  const int qt = blockIdx.x, h = blockIdx.y, b = blockIdx.z;
  const int tid = threadIdx.x;
  const int row = tid >> 2, dh0 = (tid & 3) * 8;
  const int rec0 = (((b * H_) + h) * QT_ + qt) * SPL_;
  float m[SPL_], w[SPL_];
  float M = -1e30f;
#pragma unroll
  for (int s = 0; s < SPL_; ++s) { m[s] = PM[(rec0 + s) * 64 + row]; M = fmaxf(M, m[s]); }
  float denom = 0.f;
#pragma unroll
  for (int s = 0; s < SPL_; ++s) {
    w[s] = __expf(m[s] - M);
    denom += w[s] * PLs[(rec0 + s) * 64 + row];
  }
  float num[8] = {};
#pragma unroll
  for (int s = 0; s < SPL_; ++s) {
    const float* po = PO + ((size_t)(rec0 + s) * 64 + row) * 32 + dh0;
    f32x4 a = *(const f32x4*)po;
    f32x4 c = *(const f32x4*)(po + 4);
#pragma unroll
    for (int j = 0; j < 4; ++j) { num[j] += w[s] * a[j]; num[4 + j] += w[s] * c[j]; }
  }
  const int n = qt * 64 + row;
  if (n < N_) {
    const float inv = 1.f / denom;
    bf8_t v;
#pragma unroll
    for (int j = 0; j < 8; ++j) v[j] = (short)f2b(num[j] * inv);
    *(bf8_t*)(aout + ((size_t)b * NPAD + n) * C_ + h * 32 + dh0) = v;
  }
}

// ---------------- output projection + bias + residual ---------------------------
__global__ __launch_bounds__(256) void oproj_k(
    const unsigned short* __restrict__ aout, const float* __restrict__ Wo,
    const float* __restrict__ bo, const float* __restrict__ query,
    float* __restrict__ out)
{
  __shared__ __align__(16) unsigned short Al[64][72];
  __shared__ __align__(16) unsigned short Bl[64][72];
  const int b = blockIdx.z, n0 = blockIdx.y * 64, d0 = blockIdx.x * 64;
  const int tid = threadIdx.x, lane = tid & 63, wv = tid >> 6;
  const int wm = wv >> 1, wn = wv & 1;
  const int sr = tid >> 2, sc = (tid & 3) * 16;
  const int fr = lane & 15, fg = lane >> 4;
  f32x4 acc[2][2] = {};

  for (int kt = 0; kt < 4; ++kt) {
    const int k0 = kt * 64;
    {  // A: bf16 copy from attn_out (rows up to NPAD are allocated)
      const unsigned short* src = aout + ((size_t)b * NPAD + n0 + sr) * C_ + k0 + sc;
      *(bf8_t*)&Al[sr][sc]     = *(const bf8_t*)src;
      *(bf8_t*)&Al[sr][sc + 8] = *(const bf8_t*)(src + 8);
    }
    stage_cvt16(&Bl[sr][sc], Wo + (size_t)(d0 + sr) * C_ + k0 + sc);
    __syncthreads();
#pragma unroll
    for (int kh = 0; kh < 2; ++kh) {
      const int ko = kh * 32 + 8 * fg;
      bf8_t af[2], bq[2];
#pragma unroll
      for (int m = 0; m < 2; ++m) {
        af[m] = *(const bf8_t*)&Al[wm * 32 + m * 16 + fr][ko];
        bq[m] = *(const bf8_t*)&Bl[wn * 32 + m * 16 + fr][ko];
      }
#pragma unroll
      for (int m = 0; m < 2; ++m)
#pragma unroll
        for (int n = 0; n < 2; ++n)
          acc[m][n] = __builtin_amdgcn_mfma_f32_16x16x32_bf16(af[m], bq[n], acc[m][n], 0, 0, 0);
    }
    __syncthreads();
  }
#pragma unroll
  for (int m = 0; m < 2; ++m)
#pragma unroll
    for (int nn = 0; nn < 2; ++nn) {
      const int d = d0 + wn * 32 + nn * 16 + fr;
      const float bb = bo[d];
#pragma unroll
      for (int r = 0; r < 4; ++r) {
        const int n = n0 + wm * 32 + m * 16 + fg * 4 + r;
        if (n < N_) {
          const size_t gi = ((size_t)b * N_ + n) * C_ + d;
          out[gi] = acc[m][nn][r] + bb + query[gi];
        }
      }
    }
}

extern "C" void kernel_launch(void* const* d_in, const int* in_sizes, int n_in,
                              void* d_out, int out_size, void* d_ws, size_t ws_size,
                              hipStream_t stream)
{
  const float* query = (const float*)d_in[0];
  const float* key   = (const float*)d_in[1];
  const float* value = (const float*)d_in[2];
  const float* qpos  = (const float*)d_in[3];
  const float* kpos  = (const float*)d_in[4];
  const float* qsine = (const float*)d_in[5];
  const float* Wqc = (const float*)d_in[6];  const float* bqc = (const float*)d_in[7];
  const float* Wqp = (const float*)d_in[8];  const float* bqp = (const float*)d_in[9];
  const float* Wqs = (const float*)d_in[10]; const float* bqs = (const float*)d_in[11];
  const float* Wkc = (const float*)d_in[12]; const float* bkc = (const float*)d_in[13];
  const float* Wkp = (const float*)d_in[14]; const float* bkp = (const float*)d_in[15];
  const float* Wv  = (const float*)d_in[16]; const float* bv  = (const float*)d_in[17];
  const float* Wo  = (const float*)d_in[18]; const float* bo  = (const float*)d_in[19];

  // workspace layout
  const size_t qcat_b = (size_t)B_ * H_ * NPAD * 64 * 2;             //  2.62 MB
  const size_t kcat_b = (size_t)B_ * H_ * L_ * 64 * 2;               // 33.55 MB
  const size_t vh_b   = (size_t)B_ * H_ * L_ * 32 * 2;               // 16.78 MB
  const size_t aout_b = (size_t)B_ * NPAD * C_ * 2;                  //  1.31 MB
  const size_t nrec   = (size_t)B_ * H_ * QT_ * SPL_;                // 1280
  const size_t po_b   = nrec * 64 * 32 * 4;                          // 10.49 MB
  const size_t pm_b   = nrec * 64 * 4;                               //  0.33 MB
  const size_t pl_b   = nrec * 64 * 4;                               //  0.33 MB
  if (ws_size < qcat_b + kcat_b + vh_b + aout_b + po_b + pm_b + pl_b) return;
  char* ws = (char*)d_ws;
  unsigned short* Qcat = (unsigned short*)(ws);
  unsigned short* Kcat = (unsigned short*)(ws + qcat_b);
  unsigned short* Vh   = (unsigned short*)(ws + qcat_b + kcat_b);
  unsigned short* aout = (unsigned short*)(ws + qcat_b + kcat_b + vh_b);
  float* PO  = (float*)(ws + qcat_b + kcat_b + vh_b + aout_b);
  float* PM  = (float*)(ws + qcat_b + kcat_b + vh_b + aout_b + po_b);
  float* PLs = (float*)(ws + qcat_b + kcat_b + vh_b + aout_b + po_b + pm_b);
  float* out = (float*)d_out;

  qproj_k  <<<dim3(4, QT_, 8),        256, 0, stream>>>(query, qpos, qsine, Wqc, bqc, Wqp, bqp, Wqs, bqs, Qcat);
  kvproj_k <<<dim3(4, 64, 8),         256, 0, stream>>>(key, kpos, value, Wkc, bkc, Wkp, bkp, Wv, bv, Kcat, Vh);
  attn_k   <<<dim3(QT_ * SPL_, 8, 8), 256, 0, stream>>>(Qcat, Kcat, Vh, PO, PM, PLs);
  combine_k<<<dim3(QT_, 8, 8),        256, 0, stream>>>(PO, PM, PLs, aout);
  oproj_k  <<<dim3(4, QT_, 8),        256, 0, stream>>>(aout, Wo, bo, query, out);
}

// Round 3
// 177.636 us; speedup vs baseline: 1.4007x; 1.0599x over previous
//
#include <hip/hip_runtime.h>
#include <hip/hip_bf16.h>

using bf8_t = __attribute__((ext_vector_type(8))) short;
using f32x4 = __attribute__((ext_vector_type(4))) float;

constexpr int B_   = 8;
constexpr int N_   = 300;
constexpr int L_   = 4096;
constexpr int C_   = 256;
constexpr int H_   = 8;
constexpr int NPAD = 320;          // 5 row-tiles of 64
constexpr int QT_  = 5;            // q tiles of 64
constexpr int SPL_ = 4;            // KV splits (flash-decoding)
constexpr int KVS_ = L_ / SPL_;    // 1024 keys per split
constexpr float SCALE = 0.125f;    // (2*32)^-0.5

__device__ __forceinline__ unsigned short f2b(float f) {
  unsigned u = __float_as_uint(f);
  u += 0x7FFFu + ((u >> 16) & 1u);          // RNE
  return (unsigned short)(u >> 16);
}

// convert 16 contiguous f32 -> 16 bf16 into LDS (dst 16B-aligned)
__device__ __forceinline__ void stage_cvt16(unsigned short* dst, const float* src) {
#pragma unroll
  for (int half = 0; half < 2; ++half) {
    f32x4 x0 = *(const f32x4*)(src + half * 8);
    f32x4 x1 = *(const f32x4*)(src + half * 8 + 4);
    bf8_t v;
#pragma unroll
    for (int j = 0; j < 4; ++j) { v[j] = (short)f2b(x0[j]); v[4 + j] = (short)f2b(x1[j]); }
    *(bf8_t*)(dst + half * 8) = v;
  }
}

__device__ __forceinline__ void stage_zero16(unsigned short* dst) {
  bf8_t v;
#pragma unroll
  for (int j = 0; j < 8; ++j) v[j] = 0;
  *(bf8_t*)(dst) = v;
  *(bf8_t*)(dst + 8) = v;
}

__device__ __forceinline__ void gload_lds16(const void* g, void* l) {
  __builtin_amdgcn_global_load_lds(
      (const __attribute__((address_space(1))) unsigned int*)g,
      (__attribute__((address_space(3))) unsigned int*)l, 16, 0, 0);
}

// ---------------- weight pre-convert: f32 -> bf16, granule-swizzled -------------
// Wsw[i][kt][d][g'] with g' = g ^ (d&7), granule = 8 bf16 (16B)
__global__ __launch_bounds__(256) void wcvt_k(
    const float* __restrict__ W0, const float* __restrict__ W1, const float* __restrict__ W2,
    unsigned short* __restrict__ Wsw)
{
  const float* W[3] = {W0, W1, W2};
  const int kt = blockIdx.x, i = blockIdx.y;
  const int d = threadIdx.x;
  const float* src = W[i] + (size_t)d * C_ + kt * 64;
  unsigned short* dst = Wsw + ((size_t)(i * 4 + kt) * 256 + d) * 64;
#pragma unroll
  for (int g = 0; g < 8; ++g) {
    f32x4 a = *(const f32x4*)(src + g * 8);
    f32x4 b = *(const f32x4*)(src + g * 8 + 4);
    bf8_t v;
#pragma unroll
    for (int j = 0; j < 4; ++j) { v[j] = (short)f2b(a[j]); v[4 + j] = (short)f2b(b[j]); }
    *(bf8_t*)(dst + (g ^ (d & 7)) * 8) = v;
  }
}

// ---------------- K-side projections (pipelined, full-width) --------------------
// i order: 0=kp, 1=kc, 2=v.  Block: 64 L-rows x 256 cols, K=256, 12 (i,kt) steps.
__global__ __launch_bounds__(256, 2) void kvproj_k(
    const float* __restrict__ xp, const float* __restrict__ xk, const float* __restrict__ xv,
    const unsigned short* __restrict__ Wsw,
    const float* __restrict__ bkp, const float* __restrict__ bkc, const float* __restrict__ bv,
    unsigned short* __restrict__ Kcat, unsigned short* __restrict__ Vh)
{
  __shared__ __align__(16) unsigned short Al[2][64 * 64];    // 16 KB
  __shared__ __align__(16) unsigned short Bl[2][256 * 64];   // 64 KB
  const int tid = threadIdx.x, lane = tid & 63, wv = tid >> 6;
  const int fr = lane & 15, fg = lane >> 4;
  const int row0 = blockIdx.x * 64;            // global row in [0, B*L)
  const int b = row0 >> 12, ll0 = row0 & (L_ - 1);
  const float* Ax[3] = {xp, xk, xv};
  const float* Bi[3] = {bkp, bkc, bv};

  const int sr = tid >> 2, sc = (tid & 3) * 16;      // A-stage: row, k-offset
  const int ag = sc >> 3;                            // first granule (even)

  f32x4 acc[16];
  f32x4 kpv[16];

  auto stageB = [&](int step, int buf) {
    const char* bsrc = (const char*)Wsw + (size_t)step * 32768;
    char* bdst = (char*)&Bl[buf][0];
#pragma unroll
    for (int c = 0; c < 8; ++c) {
      const int off = c * 4096 + wv * 1024 + lane * 16;
      gload_lds16(bsrc + off, bdst + off);
    }
  };
  auto stageA_load = [&](int step, f32x4* ar) {
    const int i = step >> 2, kt = step & 3;
    const float* src = Ax[i] + ((size_t)(row0 + sr)) * C_ + kt * 64 + sc;
#pragma unroll
    for (int j = 0; j < 4; ++j) ar[j] = *(const f32x4*)(src + j * 4);
  };
  auto stageA_write = [&](int buf, const f32x4* ar) {
    unsigned short* base = &Al[buf][sr * 64];
    bf8_t v0, v1;
#pragma unroll
    for (int j = 0; j < 4; ++j) {
      v0[j] = (short)f2b(ar[0][j]); v0[4 + j] = (short)f2b(ar[1][j]);
      v1[j] = (short)f2b(ar[2][j]); v1[4 + j] = (short)f2b(ar[3][j]);
    }
    *(bf8_t*)(base + ((ag ^ (sr & 7)) * 8))       = v0;
    *(bf8_t*)(base + (((ag | 1) ^ (sr & 7)) * 8)) = v1;
  };

  // prologue: stage step 0 into buf 0
  {
    f32x4 a0[4];
    stageA_load(0, a0);
    stageB(0, 0);
    stageA_write(0, a0);
  }
  __syncthreads();

  int cur = 0;
  const int arow = wv * 16 + fr;
  for (int step = 0; step < 12; ++step) {
    const int i = step >> 2, kt = step & 3;
    if (kt == 0) {
#pragma unroll
      for (int nt = 0; nt < 16; ++nt) acc[nt] = (f32x4){0.f, 0.f, 0.f, 0.f};
    }
    const int nxt = cur ^ 1;
    f32x4 arn[4];
    if (step < 11) {
      stageA_load(step + 1, arn);
      stageB(step + 1, nxt);
    }
    // compute from buf[cur]
    const unsigned short* Ab = &Al[cur][0];
    const unsigned short* Bb = &Bl[cur][0];
#pragma unroll
    for (int kh = 0; kh < 2; ++kh) {
      const int gx = (4 * kh + fg) ^ (fr & 7);
      bf8_t af = *(const bf8_t*)(Ab + arow * 64 + gx * 8);
#pragma unroll
      for (int nt = 0; nt < 16; ++nt) {
        bf8_t bfz = *(const bf8_t*)(Bb + (nt * 16 + fr) * 64 + gx * 8);
        acc[nt] = __builtin_amdgcn_mfma_f32_16x16x32_bf16(af, bfz, acc[nt], 0, 0, 0);
      }
    }
    if (kt == 3) {
      // write-out for matrix i
      const int mrow = wv * 16 + fg * 4;
#pragma unroll
      for (int nt = 0; nt < 16; ++nt) {
        const int d = nt * 16 + fr, h = d >> 5, dh = d & 31;
        const float bias = Bi[i][d];
#pragma unroll
        for (int r = 0; r < 4; ++r) {
          const int l = ll0 + mrow + r;
          const size_t base = ((size_t)(b * H_ + h) * L_ + l);
          const float val = acc[nt][r] + bias;
          if (i == 0) {
            kpv[nt][r] = val;
            Kcat[base * 64 + 32 + dh] = f2b(val);
          } else if (i == 1) {
            Kcat[base * 64 + dh] = f2b(val + kpv[nt][r]);
          } else {
            Vh[base * 32 + dh] = f2b(val);
          }
        }
      }
    }
    if (step < 11) stageA_write(nxt, arn);
    __syncthreads();
    cur = nxt;
  }
}

// ---------------- Q-side projections: qc,qp,qs -> Qcat[b][h][n][64] (scaled) ----
__global__ __launch_bounds__(256) void qproj_k(
    const float* __restrict__ xq, const float* __restrict__ xp, const float* __restrict__ xs,
    const float* __restrict__ Wqc, const float* __restrict__ bqc,
    const float* __restrict__ Wqp, const float* __restrict__ bqp,
    const float* __restrict__ Wqs, const float* __restrict__ bqs,
    unsigned short* __restrict__ Qcat)
{
  __shared__ __align__(16) unsigned short Al[64][72];
  __shared__ __align__(16) unsigned short Bl[64][72];
  const int b = blockIdx.z, n0 = blockIdx.y * 64, d0 = blockIdx.x * 64;
  const int tid = threadIdx.x, lane = tid & 63, wv = tid >> 6;
  const int wm = wv >> 1, wn = wv & 1;
  const int sr = tid >> 2, sc = (tid & 3) * 16;
  const int fr = lane & 15, fg = lane >> 4;
  const float* Ax[3] = {xq, xp, xs};
  const float* Bx[3] = {Wqc, Wqp, Wqs};
  const bool arow_ok = (n0 + sr) < N_;
  f32x4 acc[3][2][2] = {};

  for (int kt = 0; kt < 4; ++kt) {
    const int k0 = kt * 64;
#pragma unroll
    for (int i = 0; i < 3; ++i) {
      if (arow_ok) stage_cvt16(&Al[sr][sc], Ax[i] + ((size_t)b * N_ + n0 + sr) * C_ + k0 + sc);
      else         stage_zero16(&Al[sr][sc]);
      stage_cvt16(&Bl[sr][sc], Bx[i] + (size_t)(d0 + sr) * C_ + k0 + sc);
      __syncthreads();
#pragma unroll
      for (int kh = 0; kh < 2; ++kh) {
        const int ko = kh * 32 + 8 * fg;
        bf8_t af[2], bq[2];
#pragma unroll
        for (int m = 0; m < 2; ++m) {
          af[m] = *(const bf8_t*)&Al[wm * 32 + m * 16 + fr][ko];
          bq[m] = *(const bf8_t*)&Bl[wn * 32 + m * 16 + fr][ko];
        }
#pragma unroll
        for (int m = 0; m < 2; ++m)
#pragma unroll
          for (int n = 0; n < 2; ++n)
            acc[i][m][n] = __builtin_amdgcn_mfma_f32_16x16x32_bf16(af[m], bq[n], acc[i][m][n], 0, 0, 0);
      }
      __syncthreads();
    }
  }
#pragma unroll
  for (int m = 0; m < 2; ++m)
#pragma unroll
    for (int nn = 0; nn < 2; ++nn) {
      const int d = d0 + wn * 32 + nn * 16 + fr;
      const int h = d >> 5, dh = d & 31;
      const float b1 = bqc[d] + bqp[d];
      const float b2 = bqs[d];
#pragma unroll
      for (int r = 0; r < 4; ++r) {
        const int n = n0 + wm * 32 + m * 16 + fg * 4 + r;
        const size_t qi = (((size_t)b * H_ + h) * NPAD + n) * 64 + dh;
        float v1 = 0.f, v2 = 0.f;
        if (n < N_) {
          v1 = (acc[0][m][nn][r] + acc[1][m][nn][r] + b1) * SCALE;
          v2 = (acc[2][m][nn][r] + b2) * SCALE;
        }
        Qcat[qi]      = f2b(v1);
        Qcat[qi + 32] = f2b(v2);
      }
    }
}

// ---------------- flash attention (split-K over L): partial o,m,l per split ----
__global__ __launch_bounds__(256) void attn_k(
    const unsigned short* __restrict__ Qcat, const unsigned short* __restrict__ Kcat,
    const unsigned short* __restrict__ Vh,
    float* __restrict__ PO, float* __restrict__ PM, float* __restrict__ PLs)
{
  __shared__ __align__(16) unsigned short Kl[64][72];
  __shared__ __align__(16) unsigned short Vt[32][72];
  __shared__ __align__(16) unsigned short Pl[64][72];
  const int qt = blockIdx.x >> 2, s = blockIdx.x & 3;
  const int h = blockIdx.y, b = blockIdx.z;
  const int n0 = qt * 64;
  const int tid = threadIdx.x, lane = tid & 63, wv = tid >> 6;
  const int fr = lane & 15, fg = lane >> 4;

  const unsigned short* Qb = Qcat + ((size_t)b * H_ + h) * NPAD * 64;
  bf8_t qf[2];
  {
    const int qrow = n0 + wv * 16 + fr;
#pragma unroll
    for (int kh = 0; kh < 2; ++kh)
      qf[kh] = *(const bf8_t*)&Qb[(size_t)qrow * 64 + kh * 32 + 8 * fg];
  }
  float m_r[4], l_r[4];
#pragma unroll
  for (int r = 0; r < 4; ++r) { m_r[r] = -1e30f; l_r[r] = 0.f; }
  f32x4 o[2] = {};

  const unsigned short* KB = Kcat + ((size_t)b * H_ + h) * L_ * 64;
  const unsigned short* VB = Vh   + ((size_t)b * H_ + h) * L_ * 32;
  const int sr = tid >> 2;

  for (int kv0 = s * KVS_; kv0 < (s + 1) * KVS_; kv0 += 64) {
    {  // stage K tile (64x64)
      const int c0 = (tid & 3) * 16;
      const unsigned short* src = KB + (size_t)(kv0 + sr) * 64 + c0;
      *(bf8_t*)&Kl[sr][c0]     = *(const bf8_t*)src;
      *(bf8_t*)&Kl[sr][c0 + 8] = *(const bf8_t*)(src + 8);
    }
    {  // stage V tile transposed (Vt[dh][n])
      const int vn = tid >> 2, dh0 = (tid & 3) * 8;
      bf8_t v = *(const bf8_t*)&VB[(size_t)(kv0 + vn) * 32 + dh0];
#pragma unroll
      for (int j = 0; j < 8; ++j) Vt[dh0 + j][vn] = (unsigned short)v[j];
    }
    __syncthreads();

    f32x4 sc[4] = {};
#pragma unroll
    for (int kh = 0; kh < 2; ++kh) {
      const int ko = kh * 32 + 8 * fg;
#pragma unroll
      for (int nf = 0; nf < 4; ++nf) {
        bf8_t kf = *(const bf8_t*)&Kl[nf * 16 + fr][ko];
        sc[nf] = __builtin_amdgcn_mfma_f32_16x16x32_bf16(qf[kh], kf, sc[nf], 0, 0, 0);
      }
    }
#pragma unroll
    for (int r = 0; r < 4; ++r) {
      float mx = fmaxf(fmaxf(sc[0][r], sc[1][r]), fmaxf(sc[2][r], sc[3][r]));
      mx = fmaxf(mx, __shfl_xor(mx, 1));
      mx = fmaxf(mx, __shfl_xor(mx, 2));
      mx = fmaxf(mx, __shfl_xor(mx, 4));
      mx = fmaxf(mx, __shfl_xor(mx, 8));
      const float mnew = fmaxf(m_r[r], mx);
      const float corr = __expf(m_r[r] - mnew);
      float ps = 0.f;
#pragma unroll
      for (int nf = 0; nf < 4; ++nf) {
        const float p = __expf(sc[nf][r] - mnew);
        sc[nf][r] = p;
        ps += p;
      }
      ps += __shfl_xor(ps, 1);
      ps += __shfl_xor(ps, 2);
      ps += __shfl_xor(ps, 4);
      ps += __shfl_xor(ps, 8);
      l_r[r] = l_r[r] * corr + ps;
      m_r[r] = mnew;
      o[0][r] *= corr;
      o[1][r] *= corr;
    }
    {
      const int prow0 = wv * 16 + fg * 4;
#pragma unroll
      for (int nf = 0; nf < 4; ++nf)
#pragma unroll
        for (int r = 0; r < 4; ++r)
          Pl[prow0 + r][nf * 16 + fr] = f2b(sc[nf][r]);
    }
#pragma unroll
    for (int kh = 0; kh < 2; ++kh) {
      const int ko = kh * 32 + 8 * fg;
      bf8_t pf = *(const bf8_t*)&Pl[wv * 16 + fr][ko];
#pragma unroll
      for (int df = 0; df < 2; ++df) {
        bf8_t vf = *(const bf8_t*)&Vt[df * 16 + fr][ko];
        o[df] = __builtin_amdgcn_mfma_f32_16x16x32_bf16(pf, vf, o[df], 0, 0, 0);
      }
    }
    __syncthreads();
  }
  const int rec = (((b * H_) + h) * QT_ + qt) * SPL_ + s;
  const int row0 = wv * 16 + fg * 4;
#pragma unroll
  for (int r = 0; r < 4; ++r) {
    if (fr == 0) {
      PM [rec * 64 + row0 + r] = m_r[r];
      PLs[rec * 64 + row0 + r] = l_r[r];
    }
#pragma unroll
    for (int df = 0; df < 2; ++df)
      PO[((size_t)rec * 64 + row0 + r) * 32 + df * 16 + fr] = o[df][r];
  }
}

// ---------------- combine splits -> aout (bf16) --------------------------------
__global__ __launch_bounds__(256) void combine_k(
    const float* __restrict__ PO, const float* __restrict__ PM, const float* __restrict__ PLs,
    unsigned short* __restrict__ aout)
{
  const int qt = blockIdx.x, h = blockIdx.y, b = blockIdx.z;
  const int tid = threadIdx.x;
  const int row = tid >> 2, dh0 = (tid & 3) * 8;
  const int rec0 = (((b * H_) + h) * QT_ + qt) * SPL_;
  float m[SPL_], w[SPL_];
  float M = -1e30f;
#pragma unroll
  for (int s = 0; s < SPL_; ++s) { m[s] = PM[(rec0 + s) * 64 + row]; M = fmaxf(M, m[s]); }
  float denom = 0.f;
#pragma unroll
  for (int s = 0; s < SPL_; ++s) {
    w[s] = __expf(m[s] - M);
    denom += w[s] * PLs[(rec0 + s) * 64 + row];
  }
  float num[8] = {};
#pragma unroll
  for (int s = 0; s < SPL_; ++s) {
    const float* po = PO + ((size_t)(rec0 + s) * 64 + row) * 32 + dh0;
    f32x4 a = *(const f32x4*)po;
    f32x4 c = *(const f32x4*)(po + 4);
#pragma unroll
    for (int j = 0; j < 4; ++j) { num[j] += w[s] * a[j]; num[4 + j] += w[s] * c[j]; }
  }
  const int n = qt * 64 + row;
  if (n < N_) {
    const float inv = 1.f / denom;
    bf8_t v;
#pragma unroll
    for (int j = 0; j < 8; ++j) v[j] = (short)f2b(num[j] * inv);
    *(bf8_t*)(aout + ((size_t)b * NPAD + n) * C_ + h * 32 + dh0) = v;
  }
}

// ---------------- output projection + bias + residual ---------------------------
__global__ __launch_bounds__(256) void oproj_k(
    const unsigned short* __restrict__ aout, const float* __restrict__ Wo,
    const float* __restrict__ bo, const float* __restrict__ query,
    float* __restrict__ out)
{
  __shared__ __align__(16) unsigned short Al[64][72];
  __shared__ __align__(16) unsigned short Bl[64][72];
  const int b = blockIdx.z, n0 = blockIdx.y * 64, d0 = blockIdx.x * 64;
  const int tid = threadIdx.x, lane = tid & 63, wv = tid >> 6;
  const int wm = wv >> 1, wn = wv & 1;
  const int sr = tid >> 2, sc = (tid & 3) * 16;
  const int fr = lane & 15, fg = lane >> 4;
  f32x4 acc[2][2] = {};

  for (int kt = 0; kt < 4; ++kt) {
    const int k0 = kt * 64;
    {
      const unsigned short* src = aout + ((size_t)b * NPAD + n0 + sr) * C_ + k0 + sc;
      *(bf8_t*)&Al[sr][sc]     = *(const bf8_t*)src;
      *(bf8_t*)&Al[sr][sc + 8] = *(const bf8_t*)(src + 8);
    }
    stage_cvt16(&Bl[sr][sc], Wo + (size_t)(d0 + sr) * C_ + k0 + sc);
    __syncthreads();
#pragma unroll
    for (int kh = 0; kh < 2; ++kh) {
      const int ko = kh * 32 + 8 * fg;
      bf8_t af[2], bq[2];
#pragma unroll
      for (int m = 0; m < 2; ++m) {
        af[m] = *(const bf8_t*)&Al[wm * 32 + m * 16 + fr][ko];
        bq[m] = *(const bf8_t*)&Bl[wn * 32 + m * 16 + fr][ko];
      }
#pragma unroll
      for (int m = 0; m < 2; ++m)
#pragma unroll
        for (int n = 0; n < 2; ++n)
          acc[m][n] = __builtin_amdgcn_mfma_f32_16x16x32_bf16(af[m], bq[n], acc[m][n], 0, 0, 0);
    }
    __syncthreads();
  }
#pragma unroll
  for (int m = 0; m < 2; ++m)
#pragma unroll
    for (int nn = 0; nn < 2; ++nn) {
      const int d = d0 + wn * 32 + nn * 16 + fr;
      const float bb = bo[d];
#pragma unroll
      for (int r = 0; r < 4; ++r) {
        const int n = n0 + wm * 32 + m * 16 + fg * 4 + r;
        if (n < N_) {
          const size_t gi = ((size_t)b * N_ + n) * C_ + d;
          out[gi] = acc[m][nn][r] + bb + query[gi];
        }
      }
    }
}

extern "C" void kernel_launch(void* const* d_in, const int* in_sizes, int n_in,
                              void* d_out, int out_size, void* d_ws, size_t ws_size,
                              hipStream_t stream)
{
  const float* query = (const float*)d_in[0];
  const float* key   = (const float*)d_in[1];
  const float* value = (const float*)d_in[2];
  const float* qpos  = (const float*)d_in[3];
  const float* kpos  = (const float*)d_in[4];
  const float* qsine = (const float*)d_in[5];
  const float* Wqc = (const float*)d_in[6];  const float* bqc = (const float*)d_in[7];
  const float* Wqp = (const float*)d_in[8];  const float* bqp = (const float*)d_in[9];
  const float* Wqs = (const float*)d_in[10]; const float* bqs = (const float*)d_in[11];
  const float* Wkc = (const float*)d_in[12]; const float* bkc = (const float*)d_in[13];
  const float* Wkp = (const float*)d_in[14]; const float* bkp = (const float*)d_in[15];
  const float* Wv  = (const float*)d_in[16]; const float* bv  = (const float*)d_in[17];
  const float* Wo  = (const float*)d_in[18]; const float* bo  = (const float*)d_in[19];

  // workspace layout
  const size_t qcat_b = (size_t)B_ * H_ * NPAD * 64 * 2;             //  2.62 MB
  const size_t kcat_b = (size_t)B_ * H_ * L_ * 64 * 2;               // 33.55 MB
  const size_t vh_b   = (size_t)B_ * H_ * L_ * 32 * 2;               // 16.78 MB
  const size_t aout_b = (size_t)B_ * NPAD * C_ * 2;                  //  1.31 MB
  const size_t nrec   = (size_t)B_ * H_ * QT_ * SPL_;                // 1280
  const size_t po_b   = nrec * 64 * 32 * 4;                          // 10.49 MB
  const size_t pm_b   = nrec * 64 * 4;                               //  0.33 MB
  const size_t pl_b   = nrec * 64 * 4;                               //  0.33 MB
  const size_t wsw_b  = (size_t)3 * C_ * C_ * 2;                     //  0.39 MB
  if (ws_size < qcat_b + kcat_b + vh_b + aout_b + po_b + pm_b + pl_b + wsw_b) return;
  char* ws = (char*)d_ws;
  unsigned short* Qcat = (unsigned short*)(ws);
  unsigned short* Kcat = (unsigned short*)(ws + qcat_b);
  unsigned short* Vh   = (unsigned short*)(ws + qcat_b + kcat_b);
  unsigned short* aout = (unsigned short*)(ws + qcat_b + kcat_b + vh_b);
  float* PO  = (float*)(ws + qcat_b + kcat_b + vh_b + aout_b);
  float* PM  = (float*)(ws + qcat_b + kcat_b + vh_b + aout_b + po_b);
  float* PLs = (float*)(ws + qcat_b + kcat_b + vh_b + aout_b + po_b + pm_b);
  unsigned short* Wsw = (unsigned short*)(ws + qcat_b + kcat_b + vh_b + aout_b + po_b + pm_b + pl_b);
  float* out = (float*)d_out;

  wcvt_k   <<<dim3(4, 3),             256, 0, stream>>>(Wkp, Wkc, Wv, Wsw);
  qproj_k  <<<dim3(4, QT_, 8),        256, 0, stream>>>(query, qpos, qsine, Wqc, bqc, Wqp, bqp, Wqs, bqs, Qcat);
  kvproj_k <<<dim3(512),              256, 0, stream>>>(kpos, key, value, Wsw, bkp, bkc, bv, Kcat, Vh);
  attn_k   <<<dim3(QT_ * SPL_, 8, 8), 256, 0, stream>>>(Qcat, Kcat, Vh, PO, PM, PLs);
  combine_k<<<dim3(QT_, 8, 8),        256, 0, stream>>>(PO, PM, PLs, aout);
  oproj_k  <<<dim3(4, QT_, 8),        256, 0, stream>>>(aout, Wo, bo, query, out);
}

// Round 4
// 157.068 us; speedup vs baseline: 1.5841x; 1.1310x over previous
//
#include <hip/hip_runtime.h>
#include <hip/hip_bf16.h>

using bf8_t = __attribute__((ext_vector_type(8))) short;
using u16x4 = __attribute__((ext_vector_type(4))) unsigned short;
using f32x4 = __attribute__((ext_vector_type(4))) float;

constexpr int B_   = 8;
constexpr int N_   = 300;
constexpr int L_   = 4096;
constexpr int C_   = 256;
constexpr int H_   = 8;
constexpr int NPAD = 320;          // 5 row-tiles of 64
constexpr int QT_  = 5;            // q tiles of 64
constexpr int SPL_ = 4;            // KV splits (flash-decoding)
constexpr int KVS_ = L_ / SPL_;    // 1024 keys per split
constexpr float SCALE = 0.125f;    // (2*32)^-0.5

__device__ __forceinline__ unsigned short f2b(float f) {
  unsigned u = __float_as_uint(f);
  u += 0x7FFFu + ((u >> 16) & 1u);          // RNE
  return (unsigned short)(u >> 16);
}

// convert 16 contiguous f32 -> 16 bf16 into LDS (dst 16B-aligned)
__device__ __forceinline__ void stage_cvt16(unsigned short* dst, const float* src) {
#pragma unroll
  for (int half = 0; half < 2; ++half) {
    f32x4 x0 = *(const f32x4*)(src + half * 8);
    f32x4 x1 = *(const f32x4*)(src + half * 8 + 4);
    bf8_t v;
#pragma unroll
    for (int j = 0; j < 4; ++j) { v[j] = (short)f2b(x0[j]); v[4 + j] = (short)f2b(x1[j]); }
    *(bf8_t*)(dst + half * 8) = v;
  }
}

__device__ __forceinline__ void gload_lds16(const void* g, void* l) {
  __builtin_amdgcn_global_load_lds(
      (const __attribute__((address_space(1))) unsigned int*)g,
      (__attribute__((address_space(3))) unsigned int*)l, 16, 0, 0);
}

// ---------------- weight pre-convert: f32 -> bf16, granule-swizzled -------------
// Wsw[slot][d][g'] with g' = g ^ (d&7), granule = 8 bf16 (16B), slot = i*4+kt
__global__ __launch_bounds__(256) void wcvt_k(
    const float* __restrict__ W0, const float* __restrict__ W1, const float* __restrict__ W2,
    const float* __restrict__ W3, const float* __restrict__ W4, const float* __restrict__ W5,
    unsigned short* __restrict__ Wsw)
{
  const float* W[6] = {W0, W1, W2, W3, W4, W5};
  const int kt = blockIdx.x, i = blockIdx.y;
  const int d = threadIdx.x;
  const float* src = W[i] + (size_t)d * C_ + kt * 64;
  unsigned short* dst = Wsw + ((size_t)(i * 4 + kt) * 256 + d) * 64;
#pragma unroll
  for (int g = 0; g < 8; ++g) {
    f32x4 a = *(const f32x4*)(src + g * 8);
    f32x4 b = *(const f32x4*)(src + g * 8 + 4);
    bf8_t v;
#pragma unroll
    for (int j = 0; j < 4; ++j) { v[j] = (short)f2b(a[j]); v[4 + j] = (short)f2b(b[j]); }
    *(bf8_t*)(dst + (g ^ (d & 7)) * 8) = v;
  }
}

// ---------------- K-side projections (pipelined, full-width, coalesced stores) --
// i order: 0=kp, 1=kc (accumulates on kp), 2=v.  C computed transposed:
// acc[nt][r] = C[d = nt*16+fg*4+r][l = wv*16+fr]  ->  8-B row-contiguous stores.
__global__ __launch_bounds__(256, 2) void kvproj_k(
    const float* __restrict__ xp, const float* __restrict__ xk, const float* __restrict__ xv,
    const unsigned short* __restrict__ Wsw,
    const float* __restrict__ bkp, const float* __restrict__ bkc, const float* __restrict__ bv,
    unsigned short* __restrict__ Kc, unsigned short* __restrict__ Kp, unsigned short* __restrict__ Vh)
{
  __shared__ __align__(16) unsigned short Al[2][64 * 64];    // 16 KB
  __shared__ __align__(16) unsigned short Bl[2][256 * 64];   // 64 KB
  const int tid = threadIdx.x, lane = tid & 63, wv = tid >> 6;
  const int fr = lane & 15, fg = lane >> 4;
  const int row0 = blockIdx.x * 64;
  const int b = row0 >> 12, ll0 = row0 & (L_ - 1);
  const float* Ax[3] = {xp, xk, xv};

  const int sr = tid >> 2, sc = (tid & 3) * 16;
  const int ag = sc >> 3;

  f32x4 acc[16];

  auto stageB = [&](int step, int buf) {
    const char* bsrc = (const char*)Wsw + (size_t)step * 32768;
    char* bdst = (char*)&Bl[buf][0];
#pragma unroll
    for (int c = 0; c < 8; ++c) {
      const int off = c * 4096 + wv * 1024 + lane * 16;
      gload_lds16(bsrc + off, bdst + off);
    }
  };
  auto stageA_load = [&](int step, f32x4* ar) {
    const int i = step >> 2, kt = step & 3;
    const float* src = Ax[i] + ((size_t)(row0 + sr)) * C_ + kt * 64 + sc;
#pragma unroll
    for (int j = 0; j < 4; ++j) ar[j] = *(const f32x4*)(src + j * 4);
  };
  auto stageA_write = [&](int buf, const f32x4* ar) {
    unsigned short* base = &Al[buf][sr * 64];
    bf8_t v0, v1;
#pragma unroll
    for (int j = 0; j < 4; ++j) {
      v0[j] = (short)f2b(ar[0][j]); v0[4 + j] = (short)f2b(ar[1][j]);
      v1[j] = (short)f2b(ar[2][j]); v1[4 + j] = (short)f2b(ar[3][j]);
    }
    *(bf8_t*)(base + ((ag ^ (sr & 7)) * 8))       = v0;
    *(bf8_t*)(base + (((ag | 1) ^ (sr & 7)) * 8)) = v1;
  };

  {  // prologue
    f32x4 a0[4];
    stageA_load(0, a0);
    stageB(0, 0);
    stageA_write(0, a0);
  }
  __syncthreads();

  int cur = 0;
  const int xrow = wv * 16 + fr;
  const int l_out = ll0 + wv * 16 + fr;
  for (int step = 0; step < 12; ++step) {
    const int i = step >> 2, kt = step & 3;
    if (kt == 0 && i != 1) {   // i=1 (kc) accumulates on top of kp
#pragma unroll
      for (int nt = 0; nt < 16; ++nt) acc[nt] = (f32x4){0.f, 0.f, 0.f, 0.f};
    }
    const int nxt = cur ^ 1;
    f32x4 arn[4];
    if (step < 11) {
      stageA_load(step + 1, arn);
      stageB(step + 1, nxt);
    }
    const unsigned short* Ab = &Al[cur][0];
    const unsigned short* Bb = &Bl[cur][0];
#pragma unroll
    for (int kh = 0; kh < 2; ++kh) {
      const int gx = (4 * kh + fg) ^ (fr & 7);
      bf8_t xf = *(const bf8_t*)(Ab + xrow * 64 + gx * 8);
#pragma unroll
      for (int nt = 0; nt < 16; ++nt) {
        bf8_t wf = *(const bf8_t*)(Bb + (nt * 16 + fr) * 64 + gx * 8);
        acc[nt] = __builtin_amdgcn_mfma_f32_16x16x32_bf16(wf, xf, acc[nt], 0, 0, 0);
      }
    }
    if (kt == 3) {
      unsigned short* outp = (i == 0) ? Kp : (i == 1) ? Kc : Vh;
      const float* bp = (i == 2) ? bv : bkp;
#pragma unroll
      for (int nt = 0; nt < 16; ++nt) {
        const int d0 = nt * 16 + fg * 4;
        f32x4 bb = *(const f32x4*)(bp + d0);
        if (i == 1) bb += *(const f32x4*)(bkc + d0);
        u16x4 v;
#pragma unroll
        for (int r = 0; r < 4; ++r) v[r] = f2b(acc[nt][r] + bb[r]);
        *(u16x4*)(outp + ((size_t)(b * H_ + (d0 >> 5)) * L_ + l_out) * 32 + (d0 & 31)) = v;
      }
    }
    if (step < 11) stageA_write(nxt, arn);
    __syncthreads();
    cur = nxt;
  }
}

// ---------------- Q-side projections (same structure) ---------------------------
// i order: 0=qp, 1=qc (accumulates), 2=qs.  Outputs only at steps 7 and 11.
__global__ __launch_bounds__(256, 2) void qproj_k(
    const float* __restrict__ xp, const float* __restrict__ xq, const float* __restrict__ xs,
    const unsigned short* __restrict__ Wsw,
    const float* __restrict__ bqp, const float* __restrict__ bqc, const float* __restrict__ bqs,
    unsigned short* __restrict__ Qcat)
{
  __shared__ __align__(16) unsigned short Al[2][64 * 64];
  __shared__ __align__(16) unsigned short Bl[2][256 * 64];
  const int tid = threadIdx.x, lane = tid & 63, wv = tid >> 6;
  const int fr = lane & 15, fg = lane >> 4;
  const int b = blockIdx.x / 5, n0 = (blockIdx.x % 5) * 64;
  const float* Ax[3] = {xp, xq, xs};

  const int sr = tid >> 2, sc = (tid & 3) * 16;
  const int ag = sc >> 3;
  const bool arow_ok = (n0 + sr) < N_;

  f32x4 acc[16];

  auto stageB = [&](int step, int buf) {
    const char* bsrc = (const char*)Wsw + (size_t)(12 + step) * 32768;
    char* bdst = (char*)&Bl[buf][0];
#pragma unroll
    for (int c = 0; c < 8; ++c) {
      const int off = c * 4096 + wv * 1024 + lane * 16;
      gload_lds16(bsrc + off, bdst + off);
    }
  };
  auto stageA_load = [&](int step, f32x4* ar) {
    const int i = step >> 2, kt = step & 3;
    if (arow_ok) {
      const float* src = Ax[i] + ((size_t)b * N_ + n0 + sr) * C_ + kt * 64 + sc;
#pragma unroll
      for (int j = 0; j < 4; ++j) ar[j] = *(const f32x4*)(src + j * 4);
    } else {
#pragma unroll
      for (int j = 0; j < 4; ++j) ar[j] = (f32x4){0.f, 0.f, 0.f, 0.f};
    }
  };
  auto stageA_write = [&](int buf, const f32x4* ar) {
    unsigned short* base = &Al[buf][sr * 64];
    bf8_t v0, v1;
#pragma unroll
    for (int j = 0; j < 4; ++j) {
      v0[j] = (short)f2b(ar[0][j]); v0[4 + j] = (short)f2b(ar[1][j]);
      v1[j] = (short)f2b(ar[2][j]); v1[4 + j] = (short)f2b(ar[3][j]);
    }
    *(bf8_t*)(base + ((ag ^ (sr & 7)) * 8))       = v0;
    *(bf8_t*)(base + (((ag | 1) ^ (sr & 7)) * 8)) = v1;
  };

  {  // prologue
    f32x4 a0[4];
    stageA_load(0, a0);
    stageB(0, 0);
    stageA_write(0, a0);
  }
  __syncthreads();

  int cur = 0;
  const int xrow = wv * 16 + fr;
  const int n_out = n0 + wv * 16 + fr;
  const bool ok = n_out < N_;
  for (int step = 0; step < 12; ++step) {
    const int i = step >> 2;
    if (step == 0 || step == 8) {
#pragma unroll
      for (int nt = 0; nt < 16; ++nt) acc[nt] = (f32x4){0.f, 0.f, 0.f, 0.f};
    }
    const int nxt = cur ^ 1;
    f32x4 arn[4];
    if (step < 11) {
      stageA_load(step + 1, arn);
      stageB(step + 1, nxt);
    }
    const unsigned short* Ab = &Al[cur][0];
    const unsigned short* Bb = &Bl[cur][0];
#pragma unroll
    for (int kh = 0; kh < 2; ++kh) {
      const int gx = (4 * kh + fg) ^ (fr & 7);
      bf8_t xf = *(const bf8_t*)(Ab + xrow * 64 + gx * 8);
#pragma unroll
      for (int nt = 0; nt < 16; ++nt) {
        bf8_t wf = *(const bf8_t*)(Bb + (nt * 16 + fr) * 64 + gx * 8);
        acc[nt] = __builtin_amdgcn_mfma_f32_16x16x32_bf16(wf, xf, acc[nt], 0, 0, 0);
      }
    }
    if (step == 7 || step == 11) {
      const int off = (step == 7) ? 0 : 32;
#pragma unroll
      for (int nt = 0; nt < 16; ++nt) {
        const int d0 = nt * 16 + fg * 4;
        f32x4 bb;
        if (step == 7) bb = *(const f32x4*)(bqp + d0) + *(const f32x4*)(bqc + d0);
        else           bb = *(const f32x4*)(bqs + d0);
        u16x4 v;
#pragma unroll
        for (int r = 0; r < 4; ++r) v[r] = ok ? f2b((acc[nt][r] + bb[r]) * SCALE) : (unsigned short)0;
        *(u16x4*)(Qcat + ((size_t)(b * H_ + (d0 >> 5)) * NPAD + n_out) * 64 + off + (d0 & 31)) = v;
      }
    }
    if (step < 11) stageA_write(nxt, arn);
    __syncthreads();
    cur = nxt;
  }
}

// ---------------- flash attention (split-K over L): partial o,m,l per split ----
__global__ __launch_bounds__(256) void attn_k(
    const unsigned short* __restrict__ Qcat, const unsigned short* __restrict__ Kc,
    const unsigned short* __restrict__ Kp, const unsigned short* __restrict__ Vh,
    float* __restrict__ PO, float* __restrict__ PM, float* __restrict__ PLs)
{
  __shared__ __align__(16) unsigned short Kl[64][72];
  __shared__ __align__(16) unsigned short Vt[32][72];
  __shared__ __align__(16) unsigned short Pl[64][72];
  const int qt = blockIdx.x >> 2, s = blockIdx.x & 3;
  const int h = blockIdx.y, b = blockIdx.z;
  const int n0 = qt * 64;
  const int tid = threadIdx.x, lane = tid & 63, wv = tid >> 6;
  const int fr = lane & 15, fg = lane >> 4;

  const unsigned short* Qb = Qcat + ((size_t)b * H_ + h) * NPAD * 64;
  bf8_t qf[2];
  {
    const int qrow = n0 + wv * 16 + fr;
#pragma unroll
    for (int kh = 0; kh < 2; ++kh)
      qf[kh] = *(const bf8_t*)&Qb[(size_t)qrow * 64 + kh * 32 + 8 * fg];
  }
  float m_r[4], l_r[4];
#pragma unroll
  for (int r = 0; r < 4; ++r) { m_r[r] = -1e30f; l_r[r] = 0.f; }
  f32x4 o[2] = {};

  const unsigned short* KcB = Kc + ((size_t)b * H_ + h) * L_ * 32;
  const unsigned short* KpB = Kp + ((size_t)b * H_ + h) * L_ * 32;
  const unsigned short* VB  = Vh + ((size_t)b * H_ + h) * L_ * 32;
  const int sr = tid >> 2;

  for (int kv0 = s * KVS_; kv0 < (s + 1) * KVS_; kv0 += 64) {
    {  // stage K tile (64 rows x [kc(32) | kp(32)])
      const int p8 = (tid & 3) * 8;
      *(bf8_t*)&Kl[sr][p8]      = *(const bf8_t*)(KcB + (size_t)(kv0 + sr) * 32 + p8);
      *(bf8_t*)&Kl[sr][32 + p8] = *(const bf8_t*)(KpB + (size_t)(kv0 + sr) * 32 + p8);
    }
    {  // stage V tile transposed (Vt[dh][n])
      const int vn = tid >> 2, dh0 = (tid & 3) * 8;
      bf8_t v = *(const bf8_t*)&VB[(size_t)(kv0 + vn) * 32 + dh0];
#pragma unroll
      for (int j = 0; j < 8; ++j) Vt[dh0 + j][vn] = (unsigned short)v[j];
    }
    __syncthreads();

    f32x4 sc[4] = {};
#pragma unroll
    for (int kh = 0; kh < 2; ++kh) {
      const int ko = kh * 32 + 8 * fg;
#pragma unroll
      for (int nf = 0; nf < 4; ++nf) {
        bf8_t kf = *(const bf8_t*)&Kl[nf * 16 + fr][ko];
        sc[nf] = __builtin_amdgcn_mfma_f32_16x16x32_bf16(qf[kh], kf, sc[nf], 0, 0, 0);
      }
    }
#pragma unroll
    for (int r = 0; r < 4; ++r) {
      float mx = fmaxf(fmaxf(sc[0][r], sc[1][r]), fmaxf(sc[2][r], sc[3][r]));
      mx = fmaxf(mx, __shfl_xor(mx, 1));
      mx = fmaxf(mx, __shfl_xor(mx, 2));
      mx = fmaxf(mx, __shfl_xor(mx, 4));
      mx = fmaxf(mx, __shfl_xor(mx, 8));
      const float mnew = fmaxf(m_r[r], mx);
      const float corr = __expf(m_r[r] - mnew);
      float ps = 0.f;
#pragma unroll
      for (int nf = 0; nf < 4; ++nf) {
        const float p = __expf(sc[nf][r] - mnew);
        sc[nf][r] = p;
        ps += p;
      }
      ps += __shfl_xor(ps, 1);
      ps += __shfl_xor(ps, 2);
      ps += __shfl_xor(ps, 4);
      ps += __shfl_xor(ps, 8);
      l_r[r] = l_r[r] * corr + ps;
      m_r[r] = mnew;
      o[0][r] *= corr;
      o[1][r] *= corr;
    }
    {
      const int prow0 = wv * 16 + fg * 4;
#pragma unroll
      for (int nf = 0; nf < 4; ++nf)
#pragma unroll
        for (int r = 0; r < 4; ++r)
          Pl[prow0 + r][nf * 16 + fr] = f2b(sc[nf][r]);
    }
#pragma unroll
    for (int kh = 0; kh < 2; ++kh) {
      const int ko = kh * 32 + 8 * fg;
      bf8_t pf = *(const bf8_t*)&Pl[wv * 16 + fr][ko];
#pragma unroll
      for (int df = 0; df < 2; ++df) {
        bf8_t vf = *(const bf8_t*)&Vt[df * 16 + fr][ko];
        o[df] = __builtin_amdgcn_mfma_f32_16x16x32_bf16(pf, vf, o[df], 0, 0, 0);
      }
    }
    __syncthreads();
  }
  const int rec = (((b * H_) + h) * QT_ + qt) * SPL_ + s;
  const int row0 = wv * 16 + fg * 4;
#pragma unroll
  for (int r = 0; r < 4; ++r) {
    if (fr == 0) {
      PM [rec * 64 + row0 + r] = m_r[r];
      PLs[rec * 64 + row0 + r] = l_r[r];
    }
#pragma unroll
    for (int df = 0; df < 2; ++df)
      PO[((size_t)rec * 64 + row0 + r) * 32 + df * 16 + fr] = o[df][r];
  }
}

// ---------------- combine splits -> aout (bf16) --------------------------------
__global__ __launch_bounds__(256) void combine_k(
    const float* __restrict__ PO, const float* __restrict__ PM, const float* __restrict__ PLs,
    unsigned short* __restrict__ aout)
{
  const int qt = blockIdx.x, h = blockIdx.y, b = blockIdx.z;
  const int tid = threadIdx.x;
  const int row = tid >> 2, dh0 = (tid & 3) * 8;
  const int rec0 = (((b * H_) + h) * QT_ + qt) * SPL_;
  float m[SPL_], w[SPL_];
  float M = -1e30f;
#pragma unroll
  for (int s = 0; s < SPL_; ++s) { m[s] = PM[(rec0 + s) * 64 + row]; M = fmaxf(M, m[s]); }
  float denom = 0.f;
#pragma unroll
  for (int s = 0; s < SPL_; ++s) {
    w[s] = __expf(m[s] - M);
    denom += w[s] * PLs[(rec0 + s) * 64 + row];
  }
  float num[8] = {};
#pragma unroll
  for (int s = 0; s < SPL_; ++s) {
    const float* po = PO + ((size_t)(rec0 + s) * 64 + row) * 32 + dh0;
    f32x4 a = *(const f32x4*)po;
    f32x4 c = *(const f32x4*)(po + 4);
#pragma unroll
    for (int j = 0; j < 4; ++j) { num[j] += w[s] * a[j]; num[4 + j] += w[s] * c[j]; }
  }
  const int n = qt * 64 + row;
  if (n < N_) {
    const float inv = 1.f / denom;
    bf8_t v;
#pragma unroll
    for (int j = 0; j < 8; ++j) v[j] = (short)f2b(num[j] * inv);
    *(bf8_t*)(aout + ((size_t)b * NPAD + n) * C_ + h * 32 + dh0) = v;
  }
}

// ---------------- output projection + bias + residual ---------------------------
__global__ __launch_bounds__(256) void oproj_k(
    const unsigned short* __restrict__ aout, const float* __restrict__ Wo,
    const float* __restrict__ bo, const float* __restrict__ query,
    float* __restrict__ out)
{
  __shared__ __align__(16) unsigned short Al[64][72];
  __shared__ __align__(16) unsigned short Bl[64][72];
  const int b = blockIdx.z, n0 = blockIdx.y * 64, d0 = blockIdx.x * 64;
  const int tid = threadIdx.x, lane = tid & 63, wv = tid >> 6;
  const int wm = wv >> 1, wn = wv & 1;
  const int sr = tid >> 2, sc = (tid & 3) * 16;
  const int fr = lane & 15, fg = lane >> 4;
  f32x4 acc[2][2] = {};

  for (int kt = 0; kt < 4; ++kt) {
    const int k0 = kt * 64;
    {
      const unsigned short* src = aout + ((size_t)b * NPAD + n0 + sr) * C_ + k0 + sc;
      *(bf8_t*)&Al[sr][sc]     = *(const bf8_t*)src;
      *(bf8_t*)&Al[sr][sc + 8] = *(const bf8_t*)(src + 8);
    }
    stage_cvt16(&Bl[sr][sc], Wo + (size_t)(d0 + sr) * C_ + k0 + sc);
    __syncthreads();
#pragma unroll
    for (int kh = 0; kh < 2; ++kh) {
      const int ko = kh * 32 + 8 * fg;
      bf8_t af[2], bq[2];
#pragma unroll
      for (int m = 0; m < 2; ++m) {
        af[m] = *(const bf8_t*)&Al[wm * 32 + m * 16 + fr][ko];
        bq[m] = *(const bf8_t*)&Bl[wn * 32 + m * 16 + fr][ko];
      }
#pragma unroll
      for (int m = 0; m < 2; ++m)
#pragma unroll
        for (int n = 0; n < 2; ++n)
          acc[m][n] = __builtin_amdgcn_mfma_f32_16x16x32_bf16(af[m], bq[n], acc[m][n], 0, 0, 0);
    }
    __syncthreads();
  }
#pragma unroll
  for (int m = 0; m < 2; ++m)
#pragma unroll
    for (int nn = 0; nn < 2; ++nn) {
      const int d = d0 + wn * 32 + nn * 16 + fr;
      const float bb = bo[d];
#pragma unroll
      for (int r = 0; r < 4; ++r) {
        const int n = n0 + wm * 32 + m * 16 + fg * 4 + r;
        if (n < N_) {
          const size_t gi = ((size_t)b * N_ + n) * C_ + d;
          out[gi] = acc[m][nn][r] + bb + query[gi];
        }
      }
    }
}

extern "C" void kernel_launch(void* const* d_in, const int* in_sizes, int n_in,
                              void* d_out, int out_size, void* d_ws, size_t ws_size,
                              hipStream_t stream)
{
  const float* query = (const float*)d_in[0];
  const float* key   = (const float*)d_in[1];
  const float* value = (const float*)d_in[2];
  const float* qpos  = (const float*)d_in[3];
  const float* kpos  = (const float*)d_in[4];
  const float* qsine = (const float*)d_in[5];
  const float* Wqc = (const float*)d_in[6];  const float* bqc = (const float*)d_in[7];
  const float* Wqp = (const float*)d_in[8];  const float* bqp = (const float*)d_in[9];
  const float* Wqs = (const float*)d_in[10]; const float* bqs = (const float*)d_in[11];
  const float* Wkc = (const float*)d_in[12]; const float* bkc = (const float*)d_in[13];
  const float* Wkp = (const float*)d_in[14]; const float* bkp = (const float*)d_in[15];
  const float* Wv  = (const float*)d_in[16]; const float* bv  = (const float*)d_in[17];
  const float* Wo  = (const float*)d_in[18]; const float* bo  = (const float*)d_in[19];

  // workspace layout
  const size_t qcat_b = (size_t)B_ * H_ * NPAD * 64 * 2;             //  2.62 MB
  const size_t kc_b   = (size_t)B_ * H_ * L_ * 32 * 2;               // 16.78 MB
  const size_t kp_b   = kc_b;                                        // 16.78 MB
  const size_t vh_b   = kc_b;                                        // 16.78 MB
  const size_t aout_b = (size_t)B_ * NPAD * C_ * 2;                  //  1.31 MB
  const size_t nrec   = (size_t)B_ * H_ * QT_ * SPL_;                // 1280
  const size_t po_b   = nrec * 64 * 32 * 4;                          // 10.49 MB
  const size_t pm_b   = nrec * 64 * 4;
  const size_t pl_b   = nrec * 64 * 4;
  const size_t wsw_b  = (size_t)24 * 256 * 64 * 2;                   //  0.79 MB
  if (ws_size < qcat_b + kc_b + kp_b + vh_b + aout_b + po_b + pm_b + pl_b + wsw_b) return;
  char* ws = (char*)d_ws;
  unsigned short* Qcat = (unsigned short*)(ws);
  unsigned short* Kc   = (unsigned short*)(ws + qcat_b);
  unsigned short* Kp   = (unsigned short*)(ws + qcat_b + kc_b);
  unsigned short* Vh   = (unsigned short*)(ws + qcat_b + kc_b + kp_b);
  unsigned short* aout = (unsigned short*)(ws + qcat_b + kc_b + kp_b + vh_b);
  float* PO  = (float*)(ws + qcat_b + kc_b + kp_b + vh_b + aout_b);
  float* PM  = (float*)(ws + qcat_b + kc_b + kp_b + vh_b + aout_b + po_b);
  float* PLs = (float*)(ws + qcat_b + kc_b + kp_b + vh_b + aout_b + po_b + pm_b);
  unsigned short* Wsw = (unsigned short*)(ws + qcat_b + kc_b + kp_b + vh_b + aout_b + po_b + pm_b + pl_b);
  float* out = (float*)d_out;

  wcvt_k   <<<dim3(4, 6),             256, 0, stream>>>(Wkp, Wkc, Wv, Wqp, Wqc, Wqs, Wsw);
  qproj_k  <<<dim3(B_ * QT_),         256, 0, stream>>>(qpos, query, qsine, Wsw, bqp, bqc, bqs, Qcat);
  kvproj_k <<<dim3(512),              256, 0, stream>>>(kpos, key, value, Wsw, bkp, bkc, bv, Kc, Kp, Vh);
  attn_k   <<<dim3(QT_ * SPL_, 8, 8), 256, 0, stream>>>(Qcat, Kc, Kp, Vh, PO, PM, PLs);
  combine_k<<<dim3(QT_, 8, 8),        256, 0, stream>>>(PO, PM, PLs, aout);
  oproj_k  <<<dim3(4, QT_, 8),        256, 0, stream>>>(aout, Wo, bo, query, out);
}